// Round 1
// baseline (307.470 us; speedup 1.0000x reference)
//
#include <hip/hip_runtime.h>

#define PZ 16
#define SMOOTH 1e-8f

// Fixed problem shape: [N, C, Z, X, Y] = [4, 2, 160, 160, 160]
constexpr int Nn = 4, Cc = 2, Zz = 160, Xx = 160, Yy = 160;
constexpr int NZ = Zz / PZ, NX = Xx / PZ, NY = Yy / PZ;   // 10,10,10
constexpr int NBLK = Nn * NZ * NX * NY * Cc;              // 8000 rows

__global__ void zero_out_kernel(float* out) { out[0] = 0.0f; }

__global__ __launch_bounds__(256)
void adaloss_kernel(const float* __restrict__ pred,
                    const float* __restrict__ gt,
                    const float* __restrict__ a_p,
                    const float* __restrict__ b_p,
                    float* __restrict__ out)
{
    // decode row id -> (n, zz, xx, yy, c); order irrelevant for the sum,
    // but keep (n, zz, xx, yy, c) for address locality.
    int bid = blockIdx.x;
    int c   = bid % Cc;  int t1 = bid / Cc;
    int yyb = t1 % NY;   t1 /= NY;
    int xxb = t1 % NX;   t1 /= NX;
    int zzb = t1 % NZ;   int n = t1 / NZ;

    const long base =
        ((((long)(n * Cc + c) * Zz + zzb * PZ) * Xx + xxb * PZ) * Yy + yyb * PZ);

    const int t    = threadIdx.x;
    const int zofs = t >> 6;      // 0..3  (z' sub-slice)
    const int idx  = t & 63;
    const int xl   = idx >> 2;    // 0..15 (x' line within slice)
    const int v    = idx & 3;     // 0..3  (float4 within 16-float y-line)

    float sp = 0.0f, sg = 0.0f, sgp = 0.0f;

    #pragma unroll
    for (int pass = 0; pass < 4; ++pass) {
        const int  zp  = zofs + pass * 4;
        const long off = base + (long)zp * (Xx * Yy) + (long)xl * Yy + v * 4;
        const float4 p = *reinterpret_cast<const float4*>(pred + off);
        const float4 g = *reinterpret_cast<const float4*>(gt + off);
        sp  += p.x + p.y + p.z + p.w;
        sg  += g.x + g.y + g.z + g.w;
        sgp += p.x * g.x + p.y * g.y + p.z * g.z + p.w * g.w;
    }

    // 64-lane wave reduction
    #pragma unroll
    for (int s = 32; s > 0; s >>= 1) {
        sp  += __shfl_down(sp,  s, 64);
        sg  += __shfl_down(sg,  s, 64);
        sgp += __shfl_down(sgp, s, 64);
    }

    __shared__ float red[3][4];
    const int wave = t >> 6;
    const int lane = t & 63;
    if (lane == 0) { red[0][wave] = sp; red[1][wave] = sg; red[2][wave] = sgp; }
    __syncthreads();

    if (t == 0) {
        const float SP  = red[0][0] + red[0][1] + red[0][2] + red[0][3];
        const float SG  = red[1][0] + red[1][1] + red[1][2] + red[1][3];
        const float SGP = red[2][0] + red[2][1] + red[2][2] + red[2][3];

        const float tp = SGP;
        const float fn = SG - SGP;
        const float fp = SP - SGP;

        const float a = a_p[0];
        const float b = b_p[0];

        const float denom = fp + fn + SMOOTH;
        const float alpha = a + b * ((fp + SMOOTH) / denom);
        const float beta  = a + b * ((fn + SMOOTH) / denom);
        const float term  =
            1.0f - (tp + SMOOTH) / (tp + alpha * fp + beta * fn + SMOOTH);

        atomicAdd(out, term);
    }
}

extern "C" void kernel_launch(void* const* d_in, const int* in_sizes, int n_in,
                              void* d_out, int out_size, void* d_ws, size_t ws_size,
                              hipStream_t stream)
{
    const float* pred = (const float*)d_in[0];
    const float* gt   = (const float*)d_in[1];
    const float* a_p  = (const float*)d_in[2];
    const float* b_p  = (const float*)d_in[3];
    float* out = (float*)d_out;

    zero_out_kernel<<<1, 1, 0, stream>>>(out);
    adaloss_kernel<<<NBLK, 256, 0, stream>>>(pred, gt, a_p, b_p, out);
}

// Round 3
// 298.528 us; speedup vs baseline: 1.0300x; 1.0300x over previous
//
#include <hip/hip_runtime.h>

#define SMOOTH 1e-8f

// Fixed problem shape: [N, C, Z, X, Y] = [4, 2, 160, 160, 160]
constexpr int Nn = 4, Cc = 2, Zz = 160, Xx = 160, Yy = 160;
constexpr int NB = 10;                       // 16^3 blocks per dim
constexpr int NROWS = Nn * NB * NB * NB * Cc;  // 8000 (block rows)
constexpr int WG1 = Nn * Cc * NB * NB * 4;     // 3200 quarter-slab workgroups

__global__ void zero_ws_kernel(float* ws, float* out) {
    int i = blockIdx.x * 256 + threadIdx.x;
    if (i < NROWS * 3) ws[i] = 0.f;
    if (i == 0) out[0] = 0.f;
}

// Kernel 1: per-(block-row) partial sums (SP, SG, SGP) via contiguous LDS staging.
// WG = (n, c, zz, xx, q4): 4 z-planes of one 16x16 (z,x) slab, full y extent.
// Each z-plane chunk = 16 x-lines * 160 y floats = 2560 floats contiguous.
__global__ __launch_bounds__(256, 6)
void partial_kernel(const float* __restrict__ pred,
                    const float* __restrict__ gt,
                    float* __restrict__ ws)
{
    __shared__ float4 sp_[640];   // one z-plane chunk, pred
    __shared__ float4 sg_[640];   // one z-plane chunk, gt

    int wg = blockIdx.x;
    const int c  = wg & 1;  wg >>= 1;
    const int q4 = wg & 3;  wg >>= 2;
    const int xx = wg % 10; wg /= 10;
    const int zz = wg % 10;
    const int n  = wg / 10;

    const int t = threadIdx.x;
    const int zbase = zz * 16 + q4 * 4;

    // float4 base index of stage-0 chunk; z-plane stride = 160*160/4 = 6400 f4
    const long planeStride = 6400L;
    const long base0 = ((long)((n * 2 + c) * 160 + zbase) * 160 + xx * 16) * 40L;

    const float4* p4 = reinterpret_cast<const float4*>(pred);
    const float4* g4 = reinterpret_cast<const float4*>(gt);

    float4 rp0, rp1, rp2, rg0, rg1, rg2;
    const bool third = (t < 128);   // 640 f4 = 2*256 + 128

    auto LOADS = [&](int s) {
        const float4* pb = p4 + base0 + (long)s * planeStride;
        const float4* gb = g4 + base0 + (long)s * planeStride;
        rp0 = pb[t]; rp1 = pb[t + 256]; if (third) rp2 = pb[t + 512];
        rg0 = gb[t]; rg1 = gb[t + 256]; if (third) rg2 = gb[t + 512];
    };
    auto WRITE = [&]() {
        sp_[t] = rp0; sp_[t + 256] = rp1; if (third) sp_[t + 512] = rp2;
        sg_[t] = rg0; sg_[t + 256] = rg1; if (third) sg_[t + 512] = rg2;
    };

    // consume mapping: l = x-line (16), v = f4 slot (16); f4-in-line = v + 16j
    // yy = (v>>2) + 4j  -> accumulator index j is STATIC, q = v>>2 is thread-fixed.
    const int l = t >> 4, v = t & 15;

    float asp0 = 0, asg0 = 0, agp0 = 0;
    float asp1 = 0, asg1 = 0, agp1 = 0;
    float asp2 = 0, asg2 = 0, agp2 = 0;

    auto dotacc = [&](int idx, float& SP, float& SG, float& GP) {
        float4 p = sp_[idx], g = sg_[idx];
        SP += (p.x + p.y) + (p.z + p.w);
        SG += (g.x + g.y) + (g.z + g.w);
        GP += p.x * g.x + p.y * g.y + p.z * g.z + p.w * g.w;
    };

    LOADS(0);
    for (int s = 0; s < 4; ++s) {
        __syncthreads();                 // previous consume done, buffer free
        WRITE();                         // waits vmcnt for stage-s loads
        if (s < 3) LOADS(s + 1);         // issue next-stage loads, overlap consume
        __syncthreads();                 // staged data visible
        const int i0 = l * 40 + v;
        dotacc(i0,      asp0, asg0, agp0);       // yy = q
        dotacc(i0 + 16, asp1, asg1, agp1);       // yy = q + 4
        if (v < 8) dotacc(i0 + 32, asp2, asg2, agp2);  // yy = q + 8 (q<2)
    }
    __syncthreads();

    // wave reduce preserving q = lane bits [3:2]; xor over bits {0,1,4,5}
#define RED4(x) x += __shfl_xor(x, 1, 64); x += __shfl_xor(x, 2, 64); \
                x += __shfl_xor(x, 16, 64); x += __shfl_xor(x, 32, 64);
    RED4(asp0) RED4(asg0) RED4(agp0)
    RED4(asp1) RED4(asg1) RED4(agp1)
    RED4(asp2) RED4(asg2) RED4(agp2)
#undef RED4

    float* red = reinterpret_cast<float*>(sp_);   // overlay: [4 waves][4 q][9]
    const int lane = t & 63, wave = t >> 6;
    if ((lane & 51) == 0) {                       // lanes 0,4,8,12
        const int q = lane >> 2;
        float* dst = red + (wave * 4 + q) * 9;
        dst[0] = asp0; dst[1] = asg0; dst[2] = agp0;
        dst[3] = asp1; dst[4] = asg1; dst[5] = agp1;
        dst[6] = asp2; dst[7] = asg2; dst[8] = agp2;
    }
    __syncthreads();

    if (t < 30) {
        const int yy = t / 3, sidx = t % 3;
        const int q = yy & 3, j = yy >> 2;
        float val = 0.f;
        #pragma unroll
        for (int w = 0; w < 4; ++w) val += red[(w * 4 + q) * 9 + j * 3 + sidx];
        const int row = (((n * 10 + zz) * 10 + xx) * 10 + yy) * 2 + c;
        atomicAdd(&ws[row * 3 + sidx], val);
    }
}

// Kernel 2: nonlinear per-row term + global sum.
__global__ __launch_bounds__(256)
void finalize_kernel(const float* __restrict__ ws,
                     const float* __restrict__ a_p,
                     const float* __restrict__ b_p,
                     float* __restrict__ out)
{
    const int r = blockIdx.x * 256 + threadIdx.x;
    float term = 0.f;
    if (r < NROWS) {
        const float SP = ws[r * 3], SG = ws[r * 3 + 1], SGP = ws[r * 3 + 2];
        const float tp = SGP;
        const float fn = SG - SGP;
        const float fp = SP - SGP;
        const float a = a_p[0], b = b_p[0];
        const float denom = fp + fn + SMOOTH;
        const float alpha = a + b * ((fp + SMOOTH) / denom);
        const float beta  = a + b * ((fn + SMOOTH) / denom);
        term = 1.f - (tp + SMOOTH) / (tp + alpha * fp + beta * fn + SMOOTH);
    }
    #pragma unroll
    for (int d = 32; d > 0; d >>= 1) term += __shfl_down(term, d, 64);
    if ((threadIdx.x & 63) == 0) atomicAdd(out, term);
}

extern "C" void kernel_launch(void* const* d_in, const int* in_sizes, int n_in,
                              void* d_out, int out_size, void* d_ws, size_t ws_size,
                              hipStream_t stream)
{
    const float* pred = (const float*)d_in[0];
    const float* gt   = (const float*)d_in[1];
    const float* a_p  = (const float*)d_in[2];
    const float* b_p  = (const float*)d_in[3];
    float* out = (float*)d_out;
    float* ws  = (float*)d_ws;   // 8000 rows * 3 sums = 96 KB

    zero_ws_kernel<<<(NROWS * 3 + 255) / 256, 256, 0, stream>>>(ws, out);
    partial_kernel<<<WG1, 256, 0, stream>>>(pred, gt, ws);
    finalize_kernel<<<32, 256, 0, stream>>>(ws, a_p, b_p, out);
}

// Round 4
// 283.495 us; speedup vs baseline: 1.0846x; 1.0530x over previous
//
#include <hip/hip_runtime.h>

#define SMOOTH 1e-8f

// Fixed problem shape: [N, C, Z, X, Y] = [4, 2, 160, 160, 160]
constexpr int NROWS = 8000;            // (N*10*10*10*C) per-block rows
constexpr int WG1   = 3200;            // quarter-slab workgroups

__global__ void zero_out_kernel(float* out) { out[0] = 0.0f; }

// Kernel 1: per quarter-slab (n,c,zz,xx, 4 z-planes) partial sums.
// Phase 1: continuous-issue streaming loads -> per-float4 partials into LDS.
// Phase 2: yy-binned gather + reduce -> 30 floats to distinct wsq slots (no atomics).
__global__ __launch_bounds__(256, 5)
void partial_kernel(const float* __restrict__ pred,
                    const float* __restrict__ gt,
                    float* __restrict__ wsq)
{
    __shared__ float spA[2560], sgA[2560], gpA[2560];   // 30 KB SoA slot partials
    __shared__ float red[4][30];

    int wg = blockIdx.x;
    const int q4 = wg & 3;  wg >>= 2;
    const int c  = wg & 1;  wg >>= 1;
    const int xx = wg % 10; wg /= 10;
    const int zz = wg % 10;
    const int n  = wg / 10;

    const int t = threadIdx.x;
    // f4-index of quarter-slab start; one z-plane chunk = 640 contiguous f4,
    // z-plane stride = 6400 f4.
    const long base0 = ((long)((n * 2 + c) * 160 + zz * 16 + q4 * 4) * 160 + xx * 16) * 40L;

    const float4* p4 = reinterpret_cast<const float4*>(pred);
    const float4* g4 = reinterpret_cast<const float4*>(gt);

    // ---- Phase 1: no barriers, no drains; 20 independent 1KB-per-wave loads ----
    #pragma unroll
    for (int s = 0; s < 10; ++s) {
        const int  v   = s * 256 + t;          // slot = f4-linear index in quarter-slab
        const int  zp  = v / 640;              // magic-mul
        const int  rem = v - zp * 640;
        const long a   = base0 + (long)zp * 6400 + rem;
        const float4 p = p4[a];
        const float4 g = g4[a];
        spA[v] = (p.x + p.y) + (p.z + p.w);
        sgA[v] = (g.x + g.y) + (g.z + g.w);
        gpA[v] = p.x * g.x + p.y * g.y + p.z * g.z + p.w * g.w;
    }
    __syncthreads();

    // ---- Phase 2: yy-binned gather; all indices compile-time per yy ----
    // slot s = zp*640 + xl*40 + yy*4 + q  (zp:4, xl:16, yy:10, q:4)
    const int cell  = t >> 2;                  // (zp,xl): wave w owns plane zp=w
    const int q     = t & 3;
    const int sbase = (cell >> 4) * 640 + (cell & 15) * 40 + q;

    float aS[10], aG[10], aP[10];
    #pragma unroll
    for (int yy = 0; yy < 10; ++yy) {
        const int s = sbase + yy * 4;
        aS[yy] = spA[s]; aG[yy] = sgA[s]; aP[yy] = gpA[s];
    }
    #pragma unroll
    for (int yy = 0; yy < 10; ++yy) {
        #pragma unroll
        for (int d = 1; d < 64; d <<= 1) {
            aS[yy] += __shfl_xor(aS[yy], d, 64);
            aG[yy] += __shfl_xor(aG[yy], d, 64);
            aP[yy] += __shfl_xor(aP[yy], d, 64);
        }
    }

    const int lane = t & 63, wave = t >> 6;
    if (lane == 0) {
        #pragma unroll
        for (int yy = 0; yy < 10; ++yy) {
            red[wave][yy * 3 + 0] = aS[yy];
            red[wave][yy * 3 + 1] = aG[yy];
            red[wave][yy * 3 + 2] = aP[yy];
        }
    }
    __syncthreads();

    if (t < 30) {
        const float val = red[0][t] + red[1][t] + red[2][t] + red[3][t];
        const int yy   = t / 3;
        const int comp = t - yy * 3;
        const int row  = (((n * 10 + zz) * 10 + xx) * 10 + yy) * 2 + c;
        wsq[(row * 4 + q4) * 3 + comp] = val;   // distinct slot, no atomic
    }
}

// Kernel 2: combine 4 quarter contributions per row, nonlinear term, global sum.
__global__ __launch_bounds__(256)
void finalize_kernel(const float* __restrict__ wsq,
                     const float* __restrict__ a_p,
                     const float* __restrict__ b_p,
                     float* __restrict__ out)
{
    const int r = blockIdx.x * 256 + threadIdx.x;
    float term = 0.f;
    if (r < NROWS) {
        // per row: [q0:S,G,P][q1:S,G,P][q2:S,G,P][q3:S,G,P], 48B-aligned
        const float4 w0 = *reinterpret_cast<const float4*>(wsq + r * 12);
        const float4 w1 = *reinterpret_cast<const float4*>(wsq + r * 12 + 4);
        const float4 w2 = *reinterpret_cast<const float4*>(wsq + r * 12 + 8);
        const float SP  = w0.x + w0.w + w1.z + w2.y;
        const float SG  = w0.y + w1.x + w1.w + w2.z;
        const float SGP = w0.z + w1.y + w2.x + w2.w;

        const float tp = SGP;
        const float fn = SG - SGP;
        const float fp = SP - SGP;
        const float a = a_p[0], b = b_p[0];
        const float denom = fp + fn + SMOOTH;
        const float alpha = a + b * ((fp + SMOOTH) / denom);
        const float beta  = a + b * ((fn + SMOOTH) / denom);
        term = 1.f - (tp + SMOOTH) / (tp + alpha * fp + beta * fn + SMOOTH);
    }
    #pragma unroll
    for (int d = 32; d > 0; d >>= 1) term += __shfl_down(term, d, 64);
    if ((threadIdx.x & 63) == 0) atomicAdd(out, term);
}

extern "C" void kernel_launch(void* const* d_in, const int* in_sizes, int n_in,
                              void* d_out, int out_size, void* d_ws, size_t ws_size,
                              hipStream_t stream)
{
    const float* pred = (const float*)d_in[0];
    const float* gt   = (const float*)d_in[1];
    const float* a_p  = (const float*)d_in[2];
    const float* b_p  = (const float*)d_in[3];
    float* out = (float*)d_out;
    float* wsq = (float*)d_ws;   // 8000 rows * 4 quarters * 3 sums = 384 KB

    zero_out_kernel<<<1, 1, 0, stream>>>(out);
    partial_kernel<<<WG1, 256, 0, stream>>>(pred, gt, wsq);
    finalize_kernel<<<(NROWS + 255) / 256, 256, 0, stream>>>(wsq, a_p, b_p, out);
}